// Round 5
// baseline (494.126 us; speedup 1.0000x reference)
//
#include <hip/hip_runtime.h>
#include <math.h>

#define BATCH 16
#define HR 512
#define LR 128
#define N_LR (BATCH*LR*LR)   // 262144
#define N_HR (BATCH*HR*HR)   // 4194304
#define NSH 13
#define NSHIFT 169
#define TH 8                 // output rows per k_cost block
#define NW 8                 // waves per k_cost block
#define NSLOT 16             // NW * gridDim.z

template<bool B> struct BoolC { static constexpr bool value = B; };

__device__ __forceinline__ int clampi(int v, int lo, int hi){ return v<lo?lo:(v>hi?hi:v); }

// 7-tap gaussian, sigma=1, normalized; t compile-time under unroll -> folds.
__device__ __forceinline__ float gk(int t){
  const float e1 = 0.60653065971263342f;
  const float e2 = 0.13533528323661270f;
  const float e3 = 0.011108996538242306f;
  const float norm = 1.0f/(1.0f + 2.0f*(e1+e2+e3));
  int a = t < 0 ? -t : t;
  float v = (a==0) ? 1.0f : (a==1 ? e1 : (a==2 ? e2 : e3));
  return v*norm;
}

// log1p(max(.,0)) + exact 4:1 downsample; dense float4 row loads (use .y/.z).
__global__ void k_downsample(const float* __restrict__ ref, const float* __restrict__ tar,
                             float* __restrict__ wref, float* __restrict__ wtar,
                             float* __restrict__ rain){
  int i = blockIdx.x*blockDim.x + threadIdx.x;
  if (i >= N_LR) return;
  int x = i & (LR-1); int y = (i >> 7) & (LR-1); int b = i >> 14;
  int base = b*HR*HR + (4*y+1)*HR + 4*x;      // 16B aligned
  float4 r1 = *(const float4*)(ref + base);
  float4 r2 = *(const float4*)(ref + base + HR);
  float4 t1 = *(const float4*)(tar + base);
  float4 t2 = *(const float4*)(tar + base + HR);
  float r00=r1.y, r01=r1.z, r10=r2.y, r11=r2.z;
  float t00=t1.y, t01=t1.z, t10=t2.y, t11=t2.z;
  wref[i] = 0.25f*(log1pf(fmaxf(r00,0.f))+log1pf(fmaxf(r01,0.f))
                 +log1pf(fmaxf(r10,0.f))+log1pf(fmaxf(r11,0.f)));
  wtar[i] = 0.25f*(log1pf(fmaxf(t00,0.f))+log1pf(fmaxf(t01,0.f))
                 +log1pf(fmaxf(t10,0.f))+log1pf(fmaxf(t11,0.f)));
  rain[i] = (0.25f*(t00+t01+t10+t11) >= 0.1f) ? 1.0f : 0.0f;
}

// Fused separable 7x7 edge-clamped gaussian; blockIdx.z selects field.
__global__ void k_blur2(const float* __restrict__ in0, const float* __restrict__ in1,
                        float* __restrict__ out0, float* __restrict__ out1){
  const int z = blockIdx.z;
  const float* in  = z ? in1 : in0;
  float* out       = z ? out1 : out0;
  const int r0 = blockIdx.x * 16;
  const int bb = blockIdx.y;
  const int tid = threadIdx.x;
  const float* I = in + (bb<<14);
  __shared__ float raw[22][LR];
  __shared__ float hb[22][LR];
  for (int idx = tid; idx < 22*LR; idx += 256){
    int lr = idx >> 7, c = idx & (LR-1);
    int gr = clampi(r0 - 3 + lr, 0, LR-1);
    raw[lr][c] = I[(gr<<7) + c];
  }
  __syncthreads();
  for (int idx = tid; idx < 22*LR; idx += 256){
    int lr = idx >> 7, c = idx & (LR-1);
    float s = 0.f;
    #pragma unroll
    for (int t=-3;t<=3;++t) s += gk(t)*raw[lr][clampi(c+t,0,LR-1)];
    hb[lr][c] = s;
  }
  __syncthreads();
  for (int idx = tid; idx < 16*LR; idx += 256){
    int lr = idx >> 7, c = idx & (LR-1);
    int i = r0 + lr;
    float s = 0.f;
    #pragma unroll
    for (int t=-3;t<=3;++t) s += gk(t)*hb[clampi(i+t,0,LR-1) - (r0-3)][c];
    out[(bb<<14) + (i<<7) + c] = s;
  }
}

// Flow blur: decode min(best0,best1) -> (s%13-6 | s/13-6) * rain at tile load,
// 7x7 edge-clamped separable blur, multiply by rain at output.
__global__ void k_blur2f(const unsigned long long* __restrict__ best0,
                         const unsigned long long* __restrict__ best1,
                         const float* __restrict__ rain,
                         float* __restrict__ outx, float* __restrict__ outy){
  const int z = blockIdx.z;            // 0: fx, 1: fy
  float* out = z ? outy : outx;
  const int r0 = blockIdx.x * 16;
  const int bb = blockIdx.y;
  const int tid = threadIdx.x;
  __shared__ float raw[22][LR];
  __shared__ float hb[22][LR];
  for (int idx = tid; idx < 22*LR; idx += 256){
    int lr = idx >> 7, c = idx & (LR-1);
    int gr = clampi(r0 - 3 + lr, 0, LR-1);
    int gi = (bb<<14) + (gr<<7) + c;
    unsigned long long k = best0[gi];
    unsigned long long k1 = best1[gi]; if (k1 < k) k = k1;
    int s = (int)(k & 0xffffffffULL);
    int f = z ? (s / NSH - 6) : (s % NSH - 6);
    raw[lr][c] = (float)f * rain[gi];
  }
  __syncthreads();
  for (int idx = tid; idx < 22*LR; idx += 256){
    int lr = idx >> 7, c = idx & (LR-1);
    float s = 0.f;
    #pragma unroll
    for (int t=-3;t<=3;++t) s += gk(t)*raw[lr][clampi(c+t,0,LR-1)];
    hb[lr][c] = s;
  }
  __syncthreads();
  for (int idx = tid; idx < 16*LR; idx += 256){
    int lr = idx >> 7, c = idx & (LR-1);
    int i = r0 + lr;
    float s = 0.f;
    #pragma unroll
    for (int t=-3;t<=3;++t) s += gk(t)*hb[clampi(i+t,0,LR-1) - (r0-3)][c];
    int gi = (bb<<14) + (i<<7) + c;
    out[gi] = s * rain[gi];
  }
}

// --- DPP wave64 inclusive prefix (rocPRIM scan sequence), pure VALU ---
template<int CTRL, int RM>
__device__ __forceinline__ float dpp_mov0(float x){
  return __int_as_float(__builtin_amdgcn_update_dpp(0, __float_as_int(x), CTRL, RM, 0xF, true));
}
__device__ __forceinline__ float prefix64(float x){
  x += dpp_mov0<0x111,0xF>(x);   // row_shr:1
  x += dpp_mov0<0x112,0xF>(x);   // row_shr:2
  x += dpp_mov0<0x114,0xF>(x);   // row_shr:4
  x += dpp_mov0<0x118,0xF>(x);   // row_shr:8
  x += dpp_mov0<0x142,0xA>(x);   // row_bcast:15 -> rows 1,3
  x += dpp_mov0<0x143,0xC>(x);   // row_bcast:31 -> rows 2,3
  return x;
}
__device__ __forceinline__ float bperm(int addr4, float v){
  return __int_as_float(__builtin_amdgcn_ds_bpermute(addr4, __float_as_int(v)));
}

struct TapCtx { int ia0, ib0, ia1, ib1; bool la0hi, lb0ok, lb1hi, selA, selB; };

// Horizontal 21-tap zero-pad box via prefix-diff over the 128-col row held as
// (col=lane in v0, col=lane+64 in v1); register argmin update.
__device__ __forceinline__ void horiz_update(const TapCtx& tc, float v0, float v1, int s,
                                             unsigned long long& k0ref, unsigned long long& k1ref){
  float pf0 = prefix64(v0);
  float pf1 = prefix64(v1);
  float T0 = __int_as_float(__builtin_amdgcn_readlane(__float_as_int(pf0), 63));
  float va = tc.selA ? pf0 : pf1;      // va(t) = t>=10 ? pf0 : pf1
  float vb = tc.selB ? pf0 : pf1;      // vb(t) = t>=53 ? pf0 : pf1
  float a0 = bperm(tc.ia0, va) + (tc.la0hi ? T0 : 0.f);   // pf(lane+10)
  float b0 = tc.lb0ok ? bperm(tc.ib0, pf0) : 0.f;         // pf(lane-11) or 0
  float a1 = bperm(tc.ia1, pf1) + T0;                     // pf(min(lane+74,127))
  float b1 = bperm(tc.ib1, vb) + (tc.lb1hi ? T0 : 0.f);   // pf(lane+53)
  float c0 = fmaxf((a0 - b0) * (1.0f/441.0f), 0.f);
  float c1 = fmaxf((a1 - b1) * (1.0f/441.0f), 0.f);
  unsigned long long k0 = ((unsigned long long)__float_as_uint(c0) << 32) | (unsigned)s;
  unsigned long long k1 = ((unsigned long long)__float_as_uint(c1) << 32) | (unsigned)s;
  if (k0 < k0ref) k0ref = k0;
  if (k1 < k1ref) k1ref = k1;
}

// Block = (row-tile of 8, batch, shift-half z). 512 threads = 8 waves, 2 blocks/CU.
// Wave slot = z*8+w handles a contiguous dx-major t-range. prev rows in regs;
// curr 28-row register window slid one row per dy. Vertical box slid over io;
// horizontal via DPP prefix + bpermute. Register argmin, slotted LDS merge,
// per-z private best buffer (no atomics).
__global__ void __launch_bounds__(512, 4)
k_cost_flow(const float* __restrict__ prev, const float* __restrict__ curr,
            unsigned long long* __restrict__ best0,
            unsigned long long* __restrict__ best1){
  const int r0 = blockIdx.x * TH;
  const int bb = blockIdx.y;
  const int z  = blockIdx.z;
  const int tid = threadIdx.x;
  const int w = tid >> 6, lane = tid & 63;
  const float* P = prev + (bb<<14);
  const float* C = curr + (bb<<14);

  __shared__ float currT[40][LR];                 // rows r0-16..r0+23 (clamped), 20 KB
  __shared__ unsigned long long mg[4][TH*LR];     // merge slots, 32 KB

  for (int idx = tid; idx < 40*LR; idx += 512){
    int lr = idx >> 7, c = idx & (LR-1);
    int gr = clampi(r0 - 16 + lr, 0, LR-1);
    currT[lr][c] = C[(gr<<7) + c];
  }

  // prev rows r0-10..r0+17 at cols (lane, lane+64), zero-pad out of range
  float p0[28], p1[28];
  #pragma unroll
  for (int wr = 0; wr < 28; ++wr){
    int gr = r0 - 10 + wr;
    if (gr >= 0 && gr < LR){ p0[wr] = P[(gr<<7) + lane]; p1[wr] = P[(gr<<7) + lane + 64]; }
    else                   { p0[wr] = 0.f; p1[wr] = 0.f; }
  }
  __syncthreads();

  unsigned long long bk0[TH], bk1[TH];
  #pragma unroll
  for (int io = 0; io < TH; ++io){ bk0[io] = ~0ULL; bk1[io] = ~0ULL; }

  TapCtx tc;
  tc.ia0 = ((lane + 10) & 63) << 2;
  tc.ib0 = ((lane - 11) & 63) << 2;
  tc.ia1 = (min(lane + 10, 63)) << 2;
  tc.ib1 = ((lane + 53) & 63) << 2;
  tc.la0hi = (lane >= 54);
  tc.lb0ok = (lane >= 11);
  tc.lb1hi = (lane >= 11);
  tc.selA  = (lane >= 10);
  tc.selB  = (lane >= 53);

  const int slot = z*NW + w;
  const int t_lo = (NSHIFT * slot) / NSLOT;
  const int t_hi = (NSHIFT * (slot+1)) / NSLOT;

  auto walk = [&](auto CHK){
    constexpr bool chk = decltype(CHK)::value;
    int t = t_lo;
    while (t < t_hi){
      const int dxi  = t / NSH;                  // dx-major walk: t = dxi*13 + dyi
      const int dyi0 = t - dxi*NSH;
      const int ndy  = min(NSH - dyi0, t_hi - t);
      const int dx   = dxi - 6;
      const int c0   = clampi(lane + dx, 0, LR-1);
      const int c1   = clampi(lane + 64 + dx, 0, LR-1);
      float q0[28], q1[28];
      #pragma unroll
      for (int wr = 0; wr < 28; ++wr){
        q0[wr] = currT[wr + dyi0][c0];
        q1[wr] = currT[wr + dyi0][c1];
      }
      int s = dyi0*NSH + dxi;                    // reference (dy-major) shift index
      for (int rep = 0; rep < ndy; ++rep){
        float v0 = 0.f, v1 = 0.f;
        #pragma unroll
        for (int wr = 0; wr <= 20; ++wr){
          if (!chk || (r0 - 10 + wr >= 0 && r0 - 10 + wr < LR)){
            float d0 = p0[wr] - q0[wr];
            float d1 = p1[wr] - q1[wr];
            v0 = fmaf(d0, d0, v0);
            v1 = fmaf(d1, d1, v1);
          }
        }
        horiz_update(tc, v0, v1, s, bk0[0], bk1[0]);
        #pragma unroll
        for (int io = 1; io < TH; ++io){
          {
            const int wrA = io + 20;                   // add leading row
            if (!chk || (r0 - 10 + wrA < LR)){
              float d0 = p0[wrA] - q0[wrA];
              float d1 = p1[wrA] - q1[wrA];
              v0 = fmaf(d0, d0, v0);
              v1 = fmaf(d1, d1, v1);
            }
            const int wrS = io - 1;                    // subtract trailing row
            if (!chk || (r0 - 10 + wrS >= 0)){
              float d0 = p0[wrS] - q0[wrS];
              float d1 = p1[wrS] - q1[wrS];
              v0 = fmaf(-d0, d0, v0);
              v1 = fmaf(-d1, d1, v1);
            }
          }
          horiz_update(tc, v0, v1, s, bk0[io], bk1[io]);
        }
        if (rep < ndy - 1){
          #pragma unroll
          for (int wr = 0; wr < 27; ++wr){ q0[wr] = q0[wr+1]; q1[wr] = q1[wr+1]; }
          q0[27] = currT[dyi0 + rep + 28][c0];
          q1[27] = currT[dyi0 + rep + 28][c1];
        }
        s += NSH;
      }
      t += ndy;
    }
  };
  if (r0 >= 16 && r0 <= 104) walk(BoolC<false>{});
  else                       walk(BoolC<true>{});

  // slotted tree merge: slot g=w&3, waves 0-3 write, 4-7 merge, then 4-slot min
  __syncthreads();
  const int g = w & 3;
  if (w < 4){
    #pragma unroll
    for (int io = 0; io < TH; ++io){
      mg[g][io*LR + lane]      = bk0[io];
      mg[g][io*LR + lane + 64] = bk1[io];
    }
  }
  __syncthreads();
  if (w >= 4){
    #pragma unroll
    for (int io = 0; io < TH; ++io){
      unsigned long long m0 = mg[g][io*LR + lane];
      unsigned long long m1 = mg[g][io*LR + lane + 64];
      mg[g][io*LR + lane]      = (bk0[io] < m0) ? bk0[io] : m0;
      mg[g][io*LR + lane + 64] = (bk1[io] < m1) ? bk1[io] : m1;
    }
  }
  __syncthreads();
  unsigned long long* best = z ? best1 : best0;
  for (int p = tid; p < TH*LR; p += 512){
    unsigned long long k  = mg[0][p];
    unsigned long long k1 = mg[1][p]; if (k1 < k) k = k1;
    unsigned long long k2 = mg[2][p]; if (k2 < k) k = k2;
    unsigned long long k3 = mg[3][p]; if (k3 < k) k = k3;
    int io = p >> 7, jj = p & (LR-1);
    best[(bb<<14) + ((r0+io)<<7) + jj] = k;
  }
}

// Fused: flow upsample (x4), warp of ref (border bilinear), Huber+mask, mean-reduce.
__global__ void __launch_bounds__(256)
k_loss(const float* __restrict__ pred, const float* __restrict__ tar,
       const float* __restrict__ ref, const float* __restrict__ fxb,
       const float* __restrict__ fyb, float* __restrict__ out){
  const int t0 = blockIdx.x*256 + threadIdx.x;   // 0..524287
  float acc = 0.f;
  #pragma unroll
  for (int it = 0; it < 2; ++it){
    const int gq  = t0 + it*524288;
    const int b   = gq >> 16;
    const int rem = gq & 65535;
    const int y   = rem >> 7;
    const int m   = rem & 127;
    const int n = y >> 2, ky = y & 3;
    int y0; float wy;
    if (ky < 2){ y0 = max(n-1, 0); wy = (n >= 1) ? (ky == 0 ? 0.625f : 0.875f) : 0.f; }
    else       { y0 = n;           wy = (ky == 2) ? 0.125f : 0.375f; }
    const int y1 = min(y0+1, LR-1);
    const int lb = b << 14;
    const float* FxR0 = fxb + lb + (y0<<7);
    const float* FxR1 = fxb + lb + (y1<<7);
    const float* FyR0 = fyb + lb + (y0<<7);
    const float* FyR1 = fyb + lb + (y1<<7);
    const int cA = max(m-1, 0), cB = m, cC = min(m+1, LR-1);
    float xA0 = FxR0[cA], xB0 = FxR0[cB], xC0 = FxR0[cC];
    float xA1 = FxR1[cA], xB1 = FxR1[cB], xC1 = FxR1[cC];
    float yA0 = FyR0[cA], yB0 = FyR0[cB], yC0 = FyR0[cC];
    float yA1 = FyR1[cA], yB1 = FyR1[cB], yC1 = FyR1[cC];
    const bool mh = (m >= 1);
    const int hb = (b<<18) + (y<<9) + (m<<2);
    float4 pd = *(const float4*)(pred + hb);
    float4 td = *(const float4*)(tar + hb);
    const float* R = ref + (b<<18);
    const float wy1 = 1.f - wy;
    #pragma unroll
    for (int k = 0; k < 4; ++k){
      float wx;
      float lo0, hi0, lo1, hi1, flo0, fhi0, flo1, fhi1;
      if (k < 2){
        wx = mh ? (k == 0 ? 0.625f : 0.875f) : 0.f;
        lo0 = mh ? xA0 : xB0;  hi0 = mh ? xB0 : xC0;
        lo1 = mh ? xA1 : xB1;  hi1 = mh ? xB1 : xC1;
        flo0 = mh ? yA0 : yB0; fhi0 = mh ? yB0 : yC0;
        flo1 = mh ? yA1 : yB1; fhi1 = mh ? yB1 : yC1;
      } else {
        wx = (k == 2) ? 0.125f : 0.375f;
        lo0 = xB0;  hi0 = xC0;  lo1 = xB1;  hi1 = xC1;
        flo0 = yB0; fhi0 = yC0; flo1 = yB1; fhi1 = yC1;
      }
      const float w00 = wy1*(1.f-wx), w01 = wy1*wx, w10 = wy*(1.f-wx), w11 = wy*wx;
      const float fxv = 4.f*(w00*lo0 + w01*hi0 + w10*lo1 + w11*hi1);
      const float fyv = 4.f*(w00*flo0 + w01*fhi0 + w10*flo1 + w11*fhi1);
      const int x = (m<<2) + k;
      float ix = fminf(fmaxf((float)x - fxv, 0.f), (float)(HR-1));
      float iy = fminf(fmaxf((float)y - fyv, 0.f), (float)(HR-1));
      int gx0 = (int)ix; int gx1 = min(gx0+1, HR-1); float gwx = ix - (float)gx0;
      int gy0 = (int)iy; int gy1 = min(gy0+1, HR-1); float gwy = iy - (float)gy0;
      float v00 = R[(gy0<<9)+gx0], v01 = R[(gy0<<9)+gx1];
      float v10 = R[(gy1<<9)+gx0], v11 = R[(gy1<<9)+gx1];
      float tt = v00*(1.f-gwy)*(1.f-gwx) + v01*(1.f-gwy)*gwx
               + v10*gwy*(1.f-gwx)       + v11*gwy*gwx;
      float teacher = fmaxf(tt, 0.f);
      float pk = ((const float*)&pd)[k];
      float tk = ((const float*)&td)[k];
      float d  = pk - teacher;
      float ad = fabsf(d);
      float l  = ad < 0.2f ? 0.5f*d*d : 0.2f*(ad - 0.1f);
      float mm = (teacher > 0.05f || tk > 0.05f) ? 1.f : 0.f;
      acc += l*mm;
    }
  }
  acc *= (1.0f/(float)N_HR);
  #pragma unroll
  for (int o = 32; o > 0; o >>= 1) acc += __shfl_down(acc, o, 64);
  __shared__ float wsum[4];
  int lane = threadIdx.x & 63, wv = threadIdx.x >> 6;
  if (lane == 0) wsum[wv] = acc;
  __syncthreads();
  if (threadIdx.x == 0) atomicAdd(out, wsum[0]+wsum[1]+wsum[2]+wsum[3]);
}

extern "C" void kernel_launch(void* const* d_in, const int* in_sizes, int n_in,
                              void* d_out, int out_size, void* d_ws, size_t ws_size,
                              hipStream_t stream){
  const float* pred = (const float*)d_in[0];
  const float* tar  = (const float*)d_in[1];
  const float* ref  = (const float*)d_in[2];
  float* out = (float*)d_out;
  float* w = (float*)d_ws;
  float* prevW = w + 0*N_LR;
  float* currW = w + 1*N_LR;
  float* rain  = w + 2*N_LR;
  float* fxb   = w + 3*N_LR;
  float* fyb   = w + 4*N_LR;
  float* dsA   = w + 5*N_LR;
  float* dsB   = w + 6*N_LR;
  unsigned long long* best0 = (unsigned long long*)(w + 7*N_LR);   // 2 MB each
  unsigned long long* best1 = best0 + N_LR;

  hipMemsetAsync(d_out, 0, sizeof(float), stream);

  const int tb = 256, nb = (N_LR + tb - 1)/tb;
  k_downsample<<<nb, tb, 0, stream>>>(ref, tar, dsA, dsB, rain);
  k_blur2<<<dim3(8, BATCH, 2), tb, 0, stream>>>(dsA, dsB, prevW, currW);
  k_cost_flow<<<dim3(LR/TH, BATCH, 2), 512, 0, stream>>>(prevW, currW, best0, best1);
  k_blur2f<<<dim3(8, BATCH, 2), tb, 0, stream>>>(best0, best1, rain, fxb, fyb);
  k_loss<<<2048, tb, 0, stream>>>(pred, tar, ref, fxb, fyb, out);
}

// Round 6
// 199.841 us; speedup vs baseline: 2.4726x; 2.4726x over previous
//
#include <hip/hip_runtime.h>
#include <math.h>

#define BATCH 16
#define HR 512
#define LR 128
#define N_LR (BATCH*LR*LR)   // 262144
#define N_HR (BATCH*HR*HR)   // 4194304
#define NSH 13
#define NSHIFT 169
#define TH 8                 // output rows per k_cost block
#define NW 8                 // waves per k_cost block
#define NSLOT 16             // NW * gridDim.z

template<bool B> struct BoolC { static constexpr bool value = B; };

__device__ __forceinline__ int clampi(int v, int lo, int hi){ return v<lo?lo:(v>hi?hi:v); }

// 7-tap gaussian, sigma=1, normalized; t compile-time under unroll -> folds.
__device__ __forceinline__ float gk(int t){
  const float e1 = 0.60653065971263342f;
  const float e2 = 0.13533528323661270f;
  const float e3 = 0.011108996538242306f;
  const float norm = 1.0f/(1.0f + 2.0f*(e1+e2+e3));
  int a = t < 0 ? -t : t;
  float v = (a==0) ? 1.0f : (a==1 ? e1 : (a==2 ? e2 : e3));
  return v*norm;
}

// log1p(max(.,0)) + exact 4:1 downsample; dense float4 row loads (use .y/.z).
__global__ void k_downsample(const float* __restrict__ ref, const float* __restrict__ tar,
                             float* __restrict__ wref, float* __restrict__ wtar,
                             float* __restrict__ rain){
  int i = blockIdx.x*blockDim.x + threadIdx.x;
  if (i >= N_LR) return;
  int x = i & (LR-1); int y = (i >> 7) & (LR-1); int b = i >> 14;
  int base = b*HR*HR + (4*y+1)*HR + 4*x;      // 16B aligned
  float4 r1 = *(const float4*)(ref + base);
  float4 r2 = *(const float4*)(ref + base + HR);
  float4 t1 = *(const float4*)(tar + base);
  float4 t2 = *(const float4*)(tar + base + HR);
  float r00=r1.y, r01=r1.z, r10=r2.y, r11=r2.z;
  float t00=t1.y, t01=t1.z, t10=t2.y, t11=t2.z;
  wref[i] = 0.25f*(log1pf(fmaxf(r00,0.f))+log1pf(fmaxf(r01,0.f))
                 +log1pf(fmaxf(r10,0.f))+log1pf(fmaxf(r11,0.f)));
  wtar[i] = 0.25f*(log1pf(fmaxf(t00,0.f))+log1pf(fmaxf(t01,0.f))
                 +log1pf(fmaxf(t10,0.f))+log1pf(fmaxf(t11,0.f)));
  rain[i] = (0.25f*(t00+t01+t10+t11) >= 0.1f) ? 1.0f : 0.0f;
}

// Fused separable 7x7 edge-clamped gaussian; blockIdx.z selects field.
__global__ void k_blur2(const float* __restrict__ in0, const float* __restrict__ in1,
                        float* __restrict__ out0, float* __restrict__ out1){
  const int z = blockIdx.z;
  const float* in  = z ? in1 : in0;
  float* out       = z ? out1 : out0;
  const int r0 = blockIdx.x * 16;
  const int bb = blockIdx.y;
  const int tid = threadIdx.x;
  const float* I = in + (bb<<14);
  __shared__ float raw[22][LR];
  __shared__ float hb[22][LR];
  for (int idx = tid; idx < 22*LR; idx += 256){
    int lr = idx >> 7, c = idx & (LR-1);
    int gr = clampi(r0 - 3 + lr, 0, LR-1);
    raw[lr][c] = I[(gr<<7) + c];
  }
  __syncthreads();
  for (int idx = tid; idx < 22*LR; idx += 256){
    int lr = idx >> 7, c = idx & (LR-1);
    float s = 0.f;
    #pragma unroll
    for (int t=-3;t<=3;++t) s += gk(t)*raw[lr][clampi(c+t,0,LR-1)];
    hb[lr][c] = s;
  }
  __syncthreads();
  for (int idx = tid; idx < 16*LR; idx += 256){
    int lr = idx >> 7, c = idx & (LR-1);
    int i = r0 + lr;
    float s = 0.f;
    #pragma unroll
    for (int t=-3;t<=3;++t) s += gk(t)*hb[clampi(i+t,0,LR-1) - (r0-3)][c];
    out[(bb<<14) + (i<<7) + c] = s;
  }
}

// Flow blur: decode min(best0,best1) -> (s%13-6 | s/13-6) * rain at tile load,
// 7x7 edge-clamped separable blur, multiply by rain at output.
__global__ void k_blur2f(const unsigned long long* __restrict__ best0,
                         const unsigned long long* __restrict__ best1,
                         const float* __restrict__ rain,
                         float* __restrict__ outx, float* __restrict__ outy){
  const int z = blockIdx.z;            // 0: fx, 1: fy
  float* out = z ? outy : outx;
  const int r0 = blockIdx.x * 16;
  const int bb = blockIdx.y;
  const int tid = threadIdx.x;
  __shared__ float raw[22][LR];
  __shared__ float hb[22][LR];
  for (int idx = tid; idx < 22*LR; idx += 256){
    int lr = idx >> 7, c = idx & (LR-1);
    int gr = clampi(r0 - 3 + lr, 0, LR-1);
    int gi = (bb<<14) + (gr<<7) + c;
    unsigned long long k = best0[gi];
    unsigned long long k1 = best1[gi]; if (k1 < k) k = k1;
    int s = (int)(k & 0xffffffffULL);
    int f = z ? (s / NSH - 6) : (s % NSH - 6);
    raw[lr][c] = (float)f * rain[gi];
  }
  __syncthreads();
  for (int idx = tid; idx < 22*LR; idx += 256){
    int lr = idx >> 7, c = idx & (LR-1);
    float s = 0.f;
    #pragma unroll
    for (int t=-3;t<=3;++t) s += gk(t)*raw[lr][clampi(c+t,0,LR-1)];
    hb[lr][c] = s;
  }
  __syncthreads();
  for (int idx = tid; idx < 16*LR; idx += 256){
    int lr = idx >> 7, c = idx & (LR-1);
    int i = r0 + lr;
    float s = 0.f;
    #pragma unroll
    for (int t=-3;t<=3;++t) s += gk(t)*hb[clampi(i+t,0,LR-1) - (r0-3)][c];
    int gi = (bb<<14) + (i<<7) + c;
    out[gi] = s * rain[gi];
  }
}

// --- DPP wave64 inclusive prefix (rocPRIM scan sequence), pure VALU ---
template<int CTRL, int RM>
__device__ __forceinline__ float dpp_mov0(float x){
  return __int_as_float(__builtin_amdgcn_update_dpp(0, __float_as_int(x), CTRL, RM, 0xF, true));
}
__device__ __forceinline__ float prefix64(float x){
  x += dpp_mov0<0x111,0xF>(x);   // row_shr:1
  x += dpp_mov0<0x112,0xF>(x);   // row_shr:2
  x += dpp_mov0<0x114,0xF>(x);   // row_shr:4
  x += dpp_mov0<0x118,0xF>(x);   // row_shr:8
  x += dpp_mov0<0x142,0xA>(x);   // row_bcast:15 -> rows 1,3
  x += dpp_mov0<0x143,0xC>(x);   // row_bcast:31 -> rows 2,3
  return x;
}
__device__ __forceinline__ float bperm(int addr4, float v){
  return __int_as_float(__builtin_amdgcn_ds_bpermute(addr4, __float_as_int(v)));
}

struct TapCtx { int ia0, ib0, ia1, ib1; bool la0hi, lb0ok, lb1hi, selA, selB; };

// Horizontal 21-tap zero-pad box via prefix-diff over the 128-col row held as
// (col=lane in v0, col=lane+64 in v1); register argmin update.
__device__ __forceinline__ void horiz_update(const TapCtx& tc, float v0, float v1, int s,
                                             unsigned long long& k0ref, unsigned long long& k1ref){
  float pf0 = prefix64(v0);
  float pf1 = prefix64(v1);
  float T0 = __int_as_float(__builtin_amdgcn_readlane(__float_as_int(pf0), 63));
  float va = tc.selA ? pf0 : pf1;      // va(t) = t>=10 ? pf0 : pf1
  float vb = tc.selB ? pf0 : pf1;      // vb(t) = t>=53 ? pf0 : pf1
  float a0 = bperm(tc.ia0, va) + (tc.la0hi ? T0 : 0.f);   // pf(lane+10)
  float b0 = tc.lb0ok ? bperm(tc.ib0, pf0) : 0.f;         // pf(lane-11) or 0
  float a1 = bperm(tc.ia1, pf1) + T0;                     // pf(min(lane+74,127))
  float b1 = bperm(tc.ib1, vb) + (tc.lb1hi ? T0 : 0.f);   // pf(lane+53)
  float c0 = fmaxf((a0 - b0) * (1.0f/441.0f), 0.f);
  float c1 = fmaxf((a1 - b1) * (1.0f/441.0f), 0.f);
  unsigned long long k0 = ((unsigned long long)__float_as_uint(c0) << 32) | (unsigned)s;
  unsigned long long k1 = ((unsigned long long)__float_as_uint(c1) << 32) | (unsigned)s;
  if (k0 < k0ref) k0ref = k0;
  if (k1 < k1ref) k1ref = k1;
}

// Block = (row-tile of 8, batch, shift-half z). 512 threads = 8 waves.
// __launch_bounds__(512,2): register windows (p/q[28]x4) need ~104 VGPR — do NOT
// tighten to (512,4), it forces 64 VGPR and spills the windows to scratch
// (round-5 regression: 1.4 GB HBM spill traffic, 6x slowdown).
__global__ void __launch_bounds__(512, 2)
k_cost_flow(const float* __restrict__ prev, const float* __restrict__ curr,
            unsigned long long* __restrict__ best0,
            unsigned long long* __restrict__ best1){
  const int r0 = blockIdx.x * TH;
  const int bb = blockIdx.y;
  const int z  = blockIdx.z;
  const int tid = threadIdx.x;
  const int w = tid >> 6, lane = tid & 63;
  const float* P = prev + (bb<<14);
  const float* C = curr + (bb<<14);

  __shared__ float currT[40][LR];                 // rows r0-16..r0+23 (clamped), 20 KB
  __shared__ unsigned long long mg[4][TH*LR];     // merge slots, 32 KB

  for (int idx = tid; idx < 40*LR; idx += 512){
    int lr = idx >> 7, c = idx & (LR-1);
    int gr = clampi(r0 - 16 + lr, 0, LR-1);
    currT[lr][c] = C[(gr<<7) + c];
  }

  // prev rows r0-10..r0+17 at cols (lane, lane+64), zero-pad out of range
  float p0[28], p1[28];
  #pragma unroll
  for (int wr = 0; wr < 28; ++wr){
    int gr = r0 - 10 + wr;
    if (gr >= 0 && gr < LR){ p0[wr] = P[(gr<<7) + lane]; p1[wr] = P[(gr<<7) + lane + 64]; }
    else                   { p0[wr] = 0.f; p1[wr] = 0.f; }
  }
  __syncthreads();

  unsigned long long bk0[TH], bk1[TH];
  #pragma unroll
  for (int io = 0; io < TH; ++io){ bk0[io] = ~0ULL; bk1[io] = ~0ULL; }

  TapCtx tc;
  tc.ia0 = ((lane + 10) & 63) << 2;
  tc.ib0 = ((lane - 11) & 63) << 2;
  tc.ia1 = (min(lane + 10, 63)) << 2;
  tc.ib1 = ((lane + 53) & 63) << 2;
  tc.la0hi = (lane >= 54);
  tc.lb0ok = (lane >= 11);
  tc.lb1hi = (lane >= 11);
  tc.selA  = (lane >= 10);
  tc.selB  = (lane >= 53);

  const int slot = z*NW + w;
  const int t_lo = (NSHIFT * slot) / NSLOT;
  const int t_hi = (NSHIFT * (slot+1)) / NSLOT;

  auto walk = [&](auto CHK){
    constexpr bool chk = decltype(CHK)::value;
    int t = t_lo;
    while (t < t_hi){
      const int dxi  = t / NSH;                  // dx-major walk: t = dxi*13 + dyi
      const int dyi0 = t - dxi*NSH;
      const int ndy  = min(NSH - dyi0, t_hi - t);
      const int dx   = dxi - 6;
      const int c0   = clampi(lane + dx, 0, LR-1);
      const int c1   = clampi(lane + 64 + dx, 0, LR-1);
      float q0[28], q1[28];
      #pragma unroll
      for (int wr = 0; wr < 28; ++wr){
        q0[wr] = currT[wr + dyi0][c0];
        q1[wr] = currT[wr + dyi0][c1];
      }
      int s = dyi0*NSH + dxi;                    // reference (dy-major) shift index
      for (int rep = 0; rep < ndy; ++rep){
        float v0 = 0.f, v1 = 0.f;
        #pragma unroll
        for (int wr = 0; wr <= 20; ++wr){
          if (!chk || (r0 - 10 + wr >= 0 && r0 - 10 + wr < LR)){
            float d0 = p0[wr] - q0[wr];
            float d1 = p1[wr] - q1[wr];
            v0 = fmaf(d0, d0, v0);
            v1 = fmaf(d1, d1, v1);
          }
        }
        horiz_update(tc, v0, v1, s, bk0[0], bk1[0]);
        #pragma unroll
        for (int io = 1; io < TH; ++io){
          {
            const int wrA = io + 20;                   // add leading row
            if (!chk || (r0 - 10 + wrA < LR)){
              float d0 = p0[wrA] - q0[wrA];
              float d1 = p1[wrA] - q1[wrA];
              v0 = fmaf(d0, d0, v0);
              v1 = fmaf(d1, d1, v1);
            }
            const int wrS = io - 1;                    // subtract trailing row
            if (!chk || (r0 - 10 + wrS >= 0)){
              float d0 = p0[wrS] - q0[wrS];
              float d1 = p1[wrS] - q1[wrS];
              v0 = fmaf(-d0, d0, v0);
              v1 = fmaf(-d1, d1, v1);
            }
          }
          horiz_update(tc, v0, v1, s, bk0[io], bk1[io]);
        }
        if (rep < ndy - 1){
          #pragma unroll
          for (int wr = 0; wr < 27; ++wr){ q0[wr] = q0[wr+1]; q1[wr] = q1[wr+1]; }
          q0[27] = currT[dyi0 + rep + 28][c0];
          q1[27] = currT[dyi0 + rep + 28][c1];
        }
        s += NSH;
      }
      t += ndy;
    }
  };
  if (r0 >= 16 && r0 <= 104) walk(BoolC<false>{});
  else                       walk(BoolC<true>{});

  // slotted tree merge: slot g=w&3, waves 0-3 write, 4-7 merge, then 4-slot min
  __syncthreads();
  const int g = w & 3;
  if (w < 4){
    #pragma unroll
    for (int io = 0; io < TH; ++io){
      mg[g][io*LR + lane]      = bk0[io];
      mg[g][io*LR + lane + 64] = bk1[io];
    }
  }
  __syncthreads();
  if (w >= 4){
    #pragma unroll
    for (int io = 0; io < TH; ++io){
      unsigned long long m0 = mg[g][io*LR + lane];
      unsigned long long m1 = mg[g][io*LR + lane + 64];
      mg[g][io*LR + lane]      = (bk0[io] < m0) ? bk0[io] : m0;
      mg[g][io*LR + lane + 64] = (bk1[io] < m1) ? bk1[io] : m1;
    }
  }
  __syncthreads();
  unsigned long long* best = z ? best1 : best0;
  for (int p = tid; p < TH*LR; p += 512){
    unsigned long long k  = mg[0][p];
    unsigned long long k1 = mg[1][p]; if (k1 < k) k = k1;
    unsigned long long k2 = mg[2][p]; if (k2 < k) k = k2;
    unsigned long long k3 = mg[3][p]; if (k3 < k) k = k3;
    int io = p >> 7, jj = p & (LR-1);
    best[(bb<<14) + ((r0+io)<<7) + jj] = k;
  }
}

// Fused: flow upsample (x4), warp of ref (border bilinear), Huber+mask, mean-reduce.
__global__ void __launch_bounds__(256)
k_loss(const float* __restrict__ pred, const float* __restrict__ tar,
       const float* __restrict__ ref, const float* __restrict__ fxb,
       const float* __restrict__ fyb, float* __restrict__ out){
  const int t0 = blockIdx.x*256 + threadIdx.x;   // 0..524287
  float acc = 0.f;
  #pragma unroll
  for (int it = 0; it < 2; ++it){
    const int gq  = t0 + it*524288;
    const int b   = gq >> 16;
    const int rem = gq & 65535;
    const int y   = rem >> 7;
    const int m   = rem & 127;
    const int n = y >> 2, ky = y & 3;
    int y0; float wy;
    if (ky < 2){ y0 = max(n-1, 0); wy = (n >= 1) ? (ky == 0 ? 0.625f : 0.875f) : 0.f; }
    else       { y0 = n;           wy = (ky == 2) ? 0.125f : 0.375f; }
    const int y1 = min(y0+1, LR-1);
    const int lb = b << 14;
    const float* FxR0 = fxb + lb + (y0<<7);
    const float* FxR1 = fxb + lb + (y1<<7);
    const float* FyR0 = fyb + lb + (y0<<7);
    const float* FyR1 = fyb + lb + (y1<<7);
    const int cA = max(m-1, 0), cB = m, cC = min(m+1, LR-1);
    float xA0 = FxR0[cA], xB0 = FxR0[cB], xC0 = FxR0[cC];
    float xA1 = FxR1[cA], xB1 = FxR1[cB], xC1 = FxR1[cC];
    float yA0 = FyR0[cA], yB0 = FyR0[cB], yC0 = FyR0[cC];
    float yA1 = FyR1[cA], yB1 = FyR1[cB], yC1 = FyR1[cC];
    const bool mh = (m >= 1);
    const int hb = (b<<18) + (y<<9) + (m<<2);
    float4 pd = *(const float4*)(pred + hb);
    float4 td = *(const float4*)(tar + hb);
    const float* R = ref + (b<<18);
    const float wy1 = 1.f - wy;
    #pragma unroll
    for (int k = 0; k < 4; ++k){
      float wx;
      float lo0, hi0, lo1, hi1, flo0, fhi0, flo1, fhi1;
      if (k < 2){
        wx = mh ? (k == 0 ? 0.625f : 0.875f) : 0.f;
        lo0 = mh ? xA0 : xB0;  hi0 = mh ? xB0 : xC0;
        lo1 = mh ? xA1 : xB1;  hi1 = mh ? xB1 : xC1;
        flo0 = mh ? yA0 : yB0; fhi0 = mh ? yB0 : yC0;
        flo1 = mh ? yA1 : yB1; fhi1 = mh ? yB1 : yC1;
      } else {
        wx = (k == 2) ? 0.125f : 0.375f;
        lo0 = xB0;  hi0 = xC0;  lo1 = xB1;  hi1 = xC1;
        flo0 = yB0; fhi0 = yC0; flo1 = yB1; fhi1 = yC1;
      }
      const float w00 = wy1*(1.f-wx), w01 = wy1*wx, w10 = wy*(1.f-wx), w11 = wy*wx;
      const float fxv = 4.f*(w00*lo0 + w01*hi0 + w10*lo1 + w11*hi1);
      const float fyv = 4.f*(w00*flo0 + w01*fhi0 + w10*flo1 + w11*fhi1);
      const int x = (m<<2) + k;
      float ix = fminf(fmaxf((float)x - fxv, 0.f), (float)(HR-1));
      float iy = fminf(fmaxf((float)y - fyv, 0.f), (float)(HR-1));
      int gx0 = (int)ix; int gx1 = min(gx0+1, HR-1); float gwx = ix - (float)gx0;
      int gy0 = (int)iy; int gy1 = min(gy0+1, HR-1); float gwy = iy - (float)gy0;
      float v00 = R[(gy0<<9)+gx0], v01 = R[(gy0<<9)+gx1];
      float v10 = R[(gy1<<9)+gx0], v11 = R[(gy1<<9)+gx1];
      float tt = v00*(1.f-gwy)*(1.f-gwx) + v01*(1.f-gwy)*gwx
               + v10*gwy*(1.f-gwx)       + v11*gwy*gwx;
      float teacher = fmaxf(tt, 0.f);
      float pk = ((const float*)&pd)[k];
      float tk = ((const float*)&td)[k];
      float d  = pk - teacher;
      float ad = fabsf(d);
      float l  = ad < 0.2f ? 0.5f*d*d : 0.2f*(ad - 0.1f);
      float mm = (teacher > 0.05f || tk > 0.05f) ? 1.f : 0.f;
      acc += l*mm;
    }
  }
  acc *= (1.0f/(float)N_HR);
  #pragma unroll
  for (int o = 32; o > 0; o >>= 1) acc += __shfl_down(acc, o, 64);
  __shared__ float wsum[4];
  int lane = threadIdx.x & 63, wv = threadIdx.x >> 6;
  if (lane == 0) wsum[wv] = acc;
  __syncthreads();
  if (threadIdx.x == 0) atomicAdd(out, wsum[0]+wsum[1]+wsum[2]+wsum[3]);
}

extern "C" void kernel_launch(void* const* d_in, const int* in_sizes, int n_in,
                              void* d_out, int out_size, void* d_ws, size_t ws_size,
                              hipStream_t stream){
  const float* pred = (const float*)d_in[0];
  const float* tar  = (const float*)d_in[1];
  const float* ref  = (const float*)d_in[2];
  float* out = (float*)d_out;
  float* w = (float*)d_ws;
  float* prevW = w + 0*N_LR;
  float* currW = w + 1*N_LR;
  float* rain  = w + 2*N_LR;
  float* fxb   = w + 3*N_LR;
  float* fyb   = w + 4*N_LR;
  float* dsA   = w + 5*N_LR;
  float* dsB   = w + 6*N_LR;
  unsigned long long* best0 = (unsigned long long*)(w + 7*N_LR);   // 2 MB each
  unsigned long long* best1 = best0 + N_LR;

  hipMemsetAsync(d_out, 0, sizeof(float), stream);

  const int tb = 256, nb = (N_LR + tb - 1)/tb;
  k_downsample<<<nb, tb, 0, stream>>>(ref, tar, dsA, dsB, rain);
  k_blur2<<<dim3(8, BATCH, 2), tb, 0, stream>>>(dsA, dsB, prevW, currW);
  k_cost_flow<<<dim3(LR/TH, BATCH, 2), 512, 0, stream>>>(prevW, currW, best0, best1);
  k_blur2f<<<dim3(8, BATCH, 2), tb, 0, stream>>>(best0, best1, rain, fxb, fyb);
  k_loss<<<2048, tb, 0, stream>>>(pred, tar, ref, fxb, fyb, out);
}